// Round 11
// baseline (1326.027 us; speedup 1.0000x reference)
//
#include <hip/hip_runtime.h>
#include <hip/hip_bf16.h>

// GptOss grouped experts, round 11: R10 (verified best 1160us) + parameter-
// lane tuning only. gemm1: BN 320->384 (FN=6, LDS=160KB exactly, staged
// bytes/FLOP -7%), per-expert 8m x 16n block grid with ONE phantom n-column
// (block-uniform exit) -> 1024 blocks = 4.0 CU-rounds exactly (kills the
// half-idle tail round), 2D XCD chunking kept (2m x 8n chunks, pair-
// interleaved -> B slice L2-resident for both m-consumers). gemm2 unchanged
// (BN=320, 1D swizzle). 3 cvt launches fused into 1 grid-stride kernel.
// Sync structure byte-identical to R7/R10: 2-barrier counted-vmcnt loop,
// T2 XOR swizzle via inverse-swizzled source, T5 setprio on kk1 cluster.

#define TT   16384
#define DIM_ 2880
#define HID_ 2880
#define NE   8
#define TPE  2048
#define KDIM 2880
#define NT   45     // KDIM / 64
#define NX   ((long)TT * DIM_)            // 47,185,920
#define N1   ((long)NE * 2 * HID_ * DIM_) // 132,710,400
#define N2   ((long)NE * DIM_ * HID_)     // 66,355,200

typedef __attribute__((ext_vector_type(8))) short short8;
typedef __attribute__((ext_vector_type(4))) float f32x4;

__device__ __forceinline__ unsigned short f2bf(float f) {
  unsigned u = __builtin_bit_cast(unsigned, f);
  u += 0x7fffu + ((u >> 16) & 1u);   // round-to-nearest-even
  return (unsigned short)(u >> 16);
}

__device__ __forceinline__ void cvt8(const float* __restrict__ s,
                                     unsigned short* __restrict__ d) {
  float4 a = *(const float4*)s;
  float4 b = *(const float4*)(s + 4);
  union { unsigned short u[8]; short8 v; } r;
  r.u[0] = f2bf(a.x); r.u[1] = f2bf(a.y); r.u[2] = f2bf(a.z); r.u[3] = f2bf(a.w);
  r.u[4] = f2bf(b.x); r.u[5] = f2bf(b.y); r.u[6] = f2bf(b.z); r.u[7] = f2bf(b.w);
  *(short8*)d = r.v;
}

// single fused conversion pass over x | w1 | w2
__global__ void __launch_bounds__(256) cvt_all(const float* __restrict__ x,
                                               const float* __restrict__ w1,
                                               const float* __restrict__ w2,
                                               unsigned short* __restrict__ xb,
                                               unsigned short* __restrict__ w1b,
                                               unsigned short* __restrict__ w2b) {
  long i = ((long)blockIdx.x * 256 + threadIdx.x) * 8;
  if (i < NX)           cvt8(x  + i,        xb  + i);
  else if (i < NX + N1) cvt8(w1 + (i - NX), w1b + (i - NX));
  else                  cvt8(w2 + (i - NX - N1), w2b + (i - NX - N1));
}

#define GLDS(gsrc, ldst) \
  __builtin_amdgcn_global_load_lds( \
      (const __attribute__((address_space(1))) unsigned int*)(gsrc), \
      (__attribute__((address_space(3))) unsigned int*)(ldst), 16, 0, 0)

// C = A(MxK) * B(NxK)^T, bf16 in, fp32 accum. BM=256, BN=64*FN, BK=64.
// 512 threads = 8 waves (2M x 4N); per-wave 128 x (FN*16).
// CH2D: per-expert 8m x 16n grid (16th n-col phantom), 2m x 8n XCD chunks.
// LDS: dbuf x (A 32KB + B FN*8KB).
template<int FN, bool FUSE_SWIGLU, bool CH2D>
__global__ void __launch_bounds__(512, 2) gemm8(const unsigned short* __restrict__ A,
                                                const unsigned short* __restrict__ B,
                                                const float* __restrict__ bias,
                                                void* __restrict__ Cout,
                                                int M, int N) {
  constexpr int BN = 64 * FN;
  __shared__ unsigned short As[2][256 * 64];
  __shared__ unsigned short Bs[2][BN * 64];

  const int tid  = threadIdx.x;
  const int lane = tid & 63;
  const int wid  = tid >> 6;
  const int wr   = wid >> 2;        // 0..1
  const int wc   = wid & 3;         // 0..3
  const int e    = blockIdx.z;
  const int bid  = blockIdx.x;

  int m0, n0;
  if constexpr (CH2D) {
    // 8x16 padded tile grid (15 real n-tiles); 4x2 chunks of 2m x 8n.
    const int c  = bid & 7;         // XCD chunk
    const int l  = bid >> 3;        // 0..15 local, dispatch-consecutive
    const int cm = c >> 1;          // 0..3
    const int cn = c & 1;           // 0..1
    const int ni = cn * 8 + (l >> 1);
    if (ni >= N / BN) return;       // phantom n-column (block-uniform)
    m0 = (cm * 2 + (l & 1)) * 256;  // pair-interleave: alternate m fastest
    n0 = ni * BN;
  } else {
    const int ntn   = N / BN;
    const int per_e = ntn * (M / 256);
    const int swz   = (bid & 7) * (per_e >> 3) + (bid >> 3);
    m0 = (swz / ntn) * 256;
    n0 = (swz % ntn) * BN;
  }

  // staging: 8 lanes/row, 16B/lane; T2 inverse-swizzle on source column
  const int srow = tid >> 3;                         // 0..63
  const int scol = ((tid & 7) ^ (srow & 7)) << 3;    // elements
  const unsigned short* Aexp = A + ((size_t)e * M + m0 + srow) * KDIM + scol;
  const unsigned short* Bexp = B + ((size_t)e * N + n0 + srow) * KDIM + scol;

  auto stage = [&](int buf, int kt) {
    const unsigned short* asrc = Aexp + (size_t)kt * 64;
#pragma unroll
    for (int j = 0; j < 4; ++j)
      GLDS(asrc + (size_t)(j * 64) * KDIM, &As[buf][j * 4096 + tid * 8]);
    const unsigned short* bsrc = Bexp + (size_t)kt * 64;
#pragma unroll
    for (int j = 0; j < FN; ++j)
      GLDS(bsrc + (size_t)(j * 64) * KDIM, &Bs[buf][j * 4096 + tid * 8]);
  };

  // fragment-read addressing (swizzled), byte offsets; row stride 128 B
  const int arow = (wr * 128 + (lane & 15)) * 128;
  const int brow = (wc * (FN * 16) + (lane & 15)) * 128;
  const int swzb = (lane & 7) << 4;
  const int kb   = ((lane >> 4) & 3) * 16;
  const int c0 = kb ^ swzb;          // kk=0
  const int c1 = (64 + kb) ^ swzb;   // kk=1

  f32x4 acc[8][FN] = {};

  // prologue: tiles 0,1 staged (4+FN loads each); wait tile 0.
  stage(0, 0);
  stage(1, 1);
  if constexpr (FN == 6) asm volatile("s_waitcnt vmcnt(10)" ::: "memory");
  else                   asm volatile("s_waitcnt vmcnt(9)"  ::: "memory");
  __builtin_amdgcn_s_barrier();

  for (int t = 0; t < NT; ++t) {
    const int cur = t & 1;
    const char* aB = (const char*)(&As[cur][0]) + arow;
    const char* bB = (const char*)(&Bs[cur][0]) + brow;

    short8 a0[8], a1[8], b0[FN], b1[FN];
#pragma unroll
    for (int fm = 0; fm < 8; ++fm) {
      a0[fm] = *(const short8*)(aB + fm * 2048 + c0);
      a1[fm] = *(const short8*)(aB + fm * 2048 + c1);
    }
#pragma unroll
    for (int fn = 0; fn < FN; ++fn) {
      b0[fn] = *(const short8*)(bB + fn * 2048 + c0);
      b1[fn] = *(const short8*)(bB + fn * 2048 + c1);
    }

    // kk=0 MFMAs overlap kk=1 ds_reads (compiler counted lgkmcnt)
#pragma unroll
    for (int fn = 0; fn < FN; ++fn)
#pragma unroll
      for (int fm = 0; fm < 8; ++fm)
        acc[fm][fn] = __builtin_amdgcn_mfma_f32_16x16x32_bf16(a0[fm], b0[fn], acc[fm][fn], 0, 0, 0);

    // all our ds_reads done -> buffer free; barrier makes it true for all waves
    asm volatile("s_waitcnt lgkmcnt(0)" ::: "memory");
    __builtin_amdgcn_s_barrier();

    const bool more = (t + 2 < NT);
    if (more) stage(cur, t + 2);     // overwrite vacated buffer

    __builtin_amdgcn_s_setprio(1);
#pragma unroll
    for (int fn = 0; fn < FN; ++fn)
#pragma unroll
      for (int fm = 0; fm < 8; ++fm)
        acc[fm][fn] = __builtin_amdgcn_mfma_f32_16x16x32_bf16(a1[fm], b1[fn], acc[fm][fn], 0, 0, 0);
    __builtin_amdgcn_s_setprio(0);

    // counted vmcnt: wait tile t+1 complete, leave tile t+2's loads in flight
    if (more) {
      if constexpr (FN == 6) asm volatile("s_waitcnt vmcnt(10)" ::: "memory");
      else                   asm volatile("s_waitcnt vmcnt(9)"  ::: "memory");
    } else {
      asm volatile("s_waitcnt vmcnt(0)" ::: "memory");
    }
    __builtin_amdgcn_s_barrier();
  }

  // ---- epilogue
  const float* be = bias + (size_t)e * N;
  if constexpr (FUSE_SWIGLU) {
    unsigned short* ha = (unsigned short*)Cout + (size_t)e * M * (N >> 1);
#pragma unroll
    for (int fm = 0; fm < 8; ++fm)
#pragma unroll
      for (int fn = 0; fn < FN; ++fn) {
        const int col = n0 + wc * (FN * 16) + fn * 16 + (lane & 15);
        const float bc = be[col];
#pragma unroll
        for (int j = 0; j < 4; ++j) {
          const int row = m0 + wr * 128 + fm * 16 + (lane >> 4) * 4 + j;
          float v = acc[fm][fn][j] + bc;
          float p = __shfl_xor(v, 1);   // partner column (all lanes execute)
          if (!(lane & 1)) {
            float g  = fminf(v, 7.0f);
            float l2 = fminf(fmaxf(p, -7.0f), 7.0f);
            float act = g / (1.0f + __expf(-1.702f * g)) * (l2 + 1.0f);
            ha[(size_t)row * (N >> 1) + (col >> 1)] = f2bf(act);
          }
        }
      }
  } else {
    float* out = (float*)Cout + (size_t)e * M * N;
#pragma unroll
    for (int fm = 0; fm < 8; ++fm)
#pragma unroll
      for (int fn = 0; fn < FN; ++fn) {
        const int col = n0 + wc * (FN * 16) + fn * 16 + (lane & 15);
        const float bc = be[col];
#pragma unroll
        for (int j = 0; j < 4; ++j) {
          const int row = m0 + wr * 128 + fm * 16 + (lane >> 4) * 4 + j;
          out[(size_t)row * N + col] = acc[fm][fn][j] + bc;
        }
      }
  }
}

extern "C" void kernel_launch(void* const* d_in, const int* in_sizes, int n_in,
                              void* d_out, int out_size, void* d_ws, size_t ws_size,
                              hipStream_t stream) {
  const float* x  = (const float*)d_in[0];
  // d_in[1] = num_tokens_per_expert: fixed T/E split (reference ignores it)
  const float* w1 = (const float*)d_in[2];
  const float* b1 = (const float*)d_in[3];
  const float* w2 = (const float*)d_in[4];
  const float* b2 = (const float*)d_in[5];

  unsigned short* xb  = (unsigned short*)d_ws;
  unsigned short* w1b = xb  + NX;
  unsigned short* w2b = w1b + N1;
  unsigned short* ha  = w2b + N2;

  // fused fp32->bf16 conversion (x | w1 | w2), one launch at BW floor
  const long ntot = NX + N1 + N2;              // 246,251,520 (div by 2048)
  cvt_all<<<(int)(ntot / 2048), 256, 0, stream>>>(x, w1, w2, xb, w1b, w2b);

  // GEMM1 + bias + swiglu -> ha (bf16 [E][2048][2880]);
  // 8x16 padded grid -> 1024 blocks = 4.0 CU-rounds, 2D XCD chunks.
  dim3 g1(128, 1, NE);
  gemm8<6, true, true><<<g1, 512, 0, stream>>>(xb, w1b, b1, ha, TPE, 5760);

  // GEMM2 + bias -> out (fp32 [T][2880]); unchanged from R7/R10
  dim3 g2((DIM_ / 320) * (TPE / 256), 1, NE);  // 72 per expert
  gemm8<5, false, false><<<g2, 512, 0, stream>>>(ha, w2b, b2, (float*)d_out, TPE, DIM_);
}

// Round 12
// 1283.375 us; speedup vs baseline: 1.0332x; 1.0332x over previous
//
#include <hip/hip_runtime.h>
#include <hip/hip_bf16.h>

// GptOss grouped experts, round 12: same verified 2-barrier counted-vmcnt
// loop; gemm1 geometry moved to the guide's verified-best tile for this
// structure (tile table: 128^2=912 TF > 256-class=792): 128x128, 256 thr
// (4 waves 2x2, FM=FN=4), dbuf LDS 64KB -> 2 blocks/CU for natural
// MFMA/LDS phase overlap (m114). XCD chunking: 2m x 45n pair-interleaved
// (R10-proven). gemm2 byte-identical to R7/R10 (256x320, 915 TF).
// Single fused cvt launch (x|w1|w2). T2 XOR swizzle everywhere, T5 setprio.

#define TT   16384
#define DIM_ 2880
#define HID_ 2880
#define NE   8
#define TPE  2048
#define KDIM 2880
#define NT   45     // KDIM / 64
#define NX   ((long)TT * DIM_)            // 47,185,920
#define N1   ((long)NE * 2 * HID_ * DIM_) // 132,710,400
#define N2   ((long)NE * DIM_ * HID_)     // 66,355,200

typedef __attribute__((ext_vector_type(8))) short short8;
typedef __attribute__((ext_vector_type(4))) float f32x4;

__device__ __forceinline__ unsigned short f2bf(float f) {
  unsigned u = __builtin_bit_cast(unsigned, f);
  u += 0x7fffu + ((u >> 16) & 1u);   // round-to-nearest-even
  return (unsigned short)(u >> 16);
}

__device__ __forceinline__ void cvt8(const float* __restrict__ s,
                                     unsigned short* __restrict__ d) {
  float4 a = *(const float4*)s;
  float4 b = *(const float4*)(s + 4);
  union { unsigned short u[8]; short8 v; } r;
  r.u[0] = f2bf(a.x); r.u[1] = f2bf(a.y); r.u[2] = f2bf(a.z); r.u[3] = f2bf(a.w);
  r.u[4] = f2bf(b.x); r.u[5] = f2bf(b.y); r.u[6] = f2bf(b.z); r.u[7] = f2bf(b.w);
  *(short8*)d = r.v;
}

__global__ void __launch_bounds__(256) cvt_all(const float* __restrict__ x,
                                               const float* __restrict__ w1,
                                               const float* __restrict__ w2,
                                               unsigned short* __restrict__ xb,
                                               unsigned short* __restrict__ w1b,
                                               unsigned short* __restrict__ w2b) {
  long i = ((long)blockIdx.x * 256 + threadIdx.x) * 8;
  if (i < NX)           cvt8(x  + i,        xb  + i);
  else if (i < NX + N1) cvt8(w1 + (i - NX), w1b + (i - NX));
  else                  cvt8(w2 + (i - NX - N1), w2b + (i - NX - N1));
}

#define GLDS(gsrc, ldst) \
  __builtin_amdgcn_global_load_lds( \
      (const __attribute__((address_space(1))) unsigned int*)(gsrc), \
      (__attribute__((address_space(3))) unsigned int*)(ldst), 16, 0, 0)

#define MFMA_(a, b, c) __builtin_amdgcn_mfma_f32_16x16x32_bf16(a, b, c, 0, 0, 0)

// ---------------- GEMM1: 128x128 tile, 4 waves, 2 blocks/CU ----------------
// C = A(MxK) * B(NxK)^T; A=xb [E][2048][2880], B=w1b [E][5760][2880].
// Grid: (720, 1, E): 16m x 45n tiles; XCD chunk = 2m x 45n, pair-interleaved.
__global__ void __launch_bounds__(256, 2) gemm1_128(const unsigned short* __restrict__ A,
                                                    const unsigned short* __restrict__ B,
                                                    const float* __restrict__ bias,
                                                    unsigned short* __restrict__ ha) {
  __shared__ unsigned short As[2][128 * 64];   // 16 KB per buf
  __shared__ unsigned short Bs[2][128 * 64];

  const int tid  = threadIdx.x;
  const int lane = tid & 63;
  const int wid  = tid >> 6;        // 0..3
  const int wr   = wid >> 1;        // 0..1
  const int wc   = wid & 1;         // 0..1
  const int e    = blockIdx.z;
  const int bid  = blockIdx.x;

  // XCD chunking: chunk c = m-rows {2c,2c+1} x all 45 n; alternate m fastest
  const int c  = bid & 7;
  const int l  = bid >> 3;          // 0..89
  const int m0 = (c * 2 + (l & 1)) * 128;
  const int n0 = (l >> 1) * 128;

  // staging: 4 glds units per matrix; unit j = rows [32j, 32j+32)
  const int srow = tid >> 3;                         // 0..31
  const int scol = ((tid & 7) ^ (srow & 7)) << 3;    // T2 inverse-swizzle
  const unsigned short* Aexp = A + ((size_t)e * TPE + m0 + srow) * KDIM + scol;
  const unsigned short* Bexp = B + ((size_t)e * 5760 + n0 + srow) * KDIM + scol;

  auto stage = [&](int buf, int kt) {
    const unsigned short* asrc = Aexp + (size_t)kt * 64;
#pragma unroll
    for (int j = 0; j < 4; ++j)
      GLDS(asrc + (size_t)(j * 32) * KDIM, &As[buf][j * 2048 + tid * 8]);
    const unsigned short* bsrc = Bexp + (size_t)kt * 64;
#pragma unroll
    for (int j = 0; j < 4; ++j)
      GLDS(bsrc + (size_t)(j * 32) * KDIM, &Bs[buf][j * 2048 + tid * 8]);
  };

  // fragment reads (swizzled); row stride 128 B, fm/fn stride 16 rows = 2048 B
  const int arow = (wr * 64 + (lane & 15)) * 128;
  const int brow = (wc * 64 + (lane & 15)) * 128;
  const int swzb = (lane & 7) << 4;
  const int kb   = ((lane >> 4) & 3) * 16;
  const int c0 = kb ^ swzb;
  const int c1 = (64 + kb) ^ swzb;

  f32x4 acc[4][4] = {};

  stage(0, 0);
  stage(1, 1);
  asm volatile("s_waitcnt vmcnt(8)" ::: "memory");
  __builtin_amdgcn_s_barrier();

  for (int t = 0; t < NT; ++t) {
    const int cur = t & 1;
    const char* aB = (const char*)(&As[cur][0]) + arow;
    const char* bB = (const char*)(&Bs[cur][0]) + brow;

    short8 a0[4], a1[4], b0[4], b1[4];
#pragma unroll
    for (int fm = 0; fm < 4; ++fm) {
      a0[fm] = *(const short8*)(aB + fm * 2048 + c0);
      a1[fm] = *(const short8*)(aB + fm * 2048 + c1);
    }
#pragma unroll
    for (int fn = 0; fn < 4; ++fn) {
      b0[fn] = *(const short8*)(bB + fn * 2048 + c0);
      b1[fn] = *(const short8*)(bB + fn * 2048 + c1);
    }

#pragma unroll
    for (int fn = 0; fn < 4; ++fn)
#pragma unroll
      for (int fm = 0; fm < 4; ++fm)
        acc[fm][fn] = MFMA_(a0[fm], b0[fn], acc[fm][fn]);

    asm volatile("s_waitcnt lgkmcnt(0)" ::: "memory");
    __builtin_amdgcn_s_barrier();

    const bool more = (t + 2 < NT);
    if (more) stage(cur, t + 2);

    __builtin_amdgcn_s_setprio(1);
#pragma unroll
    for (int fn = 0; fn < 4; ++fn)
#pragma unroll
      for (int fm = 0; fm < 4; ++fm)
        acc[fm][fn] = MFMA_(a1[fm], b1[fn], acc[fm][fn]);
    __builtin_amdgcn_s_setprio(0);

    if (more) asm volatile("s_waitcnt vmcnt(8)" ::: "memory");
    else      asm volatile("s_waitcnt vmcnt(0)" ::: "memory");
    __builtin_amdgcn_s_barrier();
  }

  // epilogue: bias + SwiGLU -> ha bf16 [E][2048][2880]
  const float* be = bias + (size_t)e * 5760;
  unsigned short* hae = ha + (size_t)e * TPE * HID_;
#pragma unroll
  for (int fm = 0; fm < 4; ++fm)
#pragma unroll
    for (int fn = 0; fn < 4; ++fn) {
      const int col = n0 + wc * 64 + fn * 16 + (lane & 15);
      const float bc = be[col];
#pragma unroll
      for (int j = 0; j < 4; ++j) {
        const int row = m0 + wr * 64 + fm * 16 + (lane >> 4) * 4 + j;
        float v = acc[fm][fn][j] + bc;
        float p = __shfl_xor(v, 1);   // partner column
        if (!(lane & 1)) {
          float g  = fminf(v, 7.0f);
          float l2 = fminf(fmaxf(p, -7.0f), 7.0f);
          float act = g / (1.0f + __expf(-1.702f * g)) * (l2 + 1.0f);
          hae[(size_t)row * HID_ + (col >> 1)] = f2bf(act);
        }
      }
    }
}

// ---------------- GEMM2: R7/R10 verified kernel (256x320, FN=5) ------------
__global__ void __launch_bounds__(512, 2) gemm2k(const unsigned short* __restrict__ A,
                                                 const unsigned short* __restrict__ B,
                                                 const float* __restrict__ bias,
                                                 float* __restrict__ Cout,
                                                 int M, int N) {
  __shared__ unsigned short As[2][256 * 64];
  __shared__ unsigned short Bs[2][320 * 64];

  const int tid  = threadIdx.x;
  const int lane = tid & 63;
  const int wid  = tid >> 6;
  const int wr   = wid >> 2;
  const int wc   = wid & 3;
  const int e    = blockIdx.z;

  const int ntn   = N / 320;
  const int per_e = ntn * (M / 256);
  const int bid   = blockIdx.x;
  const int swz   = (bid & 7) * (per_e >> 3) + (bid >> 3);
  const int m0    = (swz / ntn) * 256;
  const int n0    = (swz % ntn) * 320;

  const int srow = tid >> 3;
  const int scol = ((tid & 7) ^ (srow & 7)) << 3;
  const unsigned short* Aexp = A + ((size_t)e * M + m0 + srow) * KDIM + scol;
  const unsigned short* Bexp = B + ((size_t)e * N + n0 + srow) * KDIM + scol;

  auto stage = [&](int buf, int kt) {
    const unsigned short* asrc = Aexp + (size_t)kt * 64;
#pragma unroll
    for (int j = 0; j < 4; ++j)
      GLDS(asrc + (size_t)(j * 64) * KDIM, &As[buf][j * 4096 + tid * 8]);
    const unsigned short* bsrc = Bexp + (size_t)kt * 64;
#pragma unroll
    for (int j = 0; j < 5; ++j)
      GLDS(bsrc + (size_t)(j * 64) * KDIM, &Bs[buf][j * 4096 + tid * 8]);
  };

  const int arow = (wr * 128 + (lane & 15)) * 128;
  const int brow = (wc * 80  + (lane & 15)) * 128;
  const int swzb = (lane & 7) << 4;
  const int kb   = ((lane >> 4) & 3) * 16;
  const int c0 = kb ^ swzb;
  const int c1 = (64 + kb) ^ swzb;

  f32x4 acc[8][5] = {};

  stage(0, 0);
  stage(1, 1);
  asm volatile("s_waitcnt vmcnt(9)" ::: "memory");
  __builtin_amdgcn_s_barrier();

  for (int t = 0; t < NT; ++t) {
    const int cur = t & 1;
    const char* aB = (const char*)(&As[cur][0]) + arow;
    const char* bB = (const char*)(&Bs[cur][0]) + brow;

    short8 a0[8], a1[8], b0[5], b1[5];
#pragma unroll
    for (int fm = 0; fm < 8; ++fm) {
      a0[fm] = *(const short8*)(aB + fm * 2048 + c0);
      a1[fm] = *(const short8*)(aB + fm * 2048 + c1);
    }
#pragma unroll
    for (int fn = 0; fn < 5; ++fn) {
      b0[fn] = *(const short8*)(bB + fn * 2048 + c0);
      b1[fn] = *(const short8*)(bB + fn * 2048 + c1);
    }

#pragma unroll
    for (int fn = 0; fn < 5; ++fn)
#pragma unroll
      for (int fm = 0; fm < 8; ++fm)
        acc[fm][fn] = MFMA_(a0[fm], b0[fn], acc[fm][fn]);

    asm volatile("s_waitcnt lgkmcnt(0)" ::: "memory");
    __builtin_amdgcn_s_barrier();

    const bool more = (t + 2 < NT);
    if (more) stage(cur, t + 2);

    __builtin_amdgcn_s_setprio(1);
#pragma unroll
    for (int fn = 0; fn < 5; ++fn)
#pragma unroll
      for (int fm = 0; fm < 8; ++fm)
        acc[fm][fn] = MFMA_(a1[fm], b1[fn], acc[fm][fn]);
    __builtin_amdgcn_s_setprio(0);

    if (more) asm volatile("s_waitcnt vmcnt(9)" ::: "memory");
    else      asm volatile("s_waitcnt vmcnt(0)" ::: "memory");
    __builtin_amdgcn_s_barrier();
  }

  const float* be = bias + (size_t)e * N;
  float* out = Cout + (size_t)e * (size_t)M * N;
#pragma unroll
  for (int fm = 0; fm < 8; ++fm)
#pragma unroll
    for (int fn = 0; fn < 5; ++fn) {
      const int col = n0 + wc * 80 + fn * 16 + (lane & 15);
      const float bc = be[col];
#pragma unroll
      for (int j = 0; j < 4; ++j) {
        const int row = m0 + wr * 128 + fm * 16 + (lane >> 4) * 4 + j;
        out[(size_t)row * N + col] = acc[fm][fn][j] + bc;
      }
    }
}

extern "C" void kernel_launch(void* const* d_in, const int* in_sizes, int n_in,
                              void* d_out, int out_size, void* d_ws, size_t ws_size,
                              hipStream_t stream) {
  const float* x  = (const float*)d_in[0];
  // d_in[1] = num_tokens_per_expert: fixed T/E split (reference ignores it)
  const float* w1 = (const float*)d_in[2];
  const float* b1 = (const float*)d_in[3];
  const float* w2 = (const float*)d_in[4];
  const float* b2 = (const float*)d_in[5];

  unsigned short* xb  = (unsigned short*)d_ws;
  unsigned short* w1b = xb  + NX;
  unsigned short* w2b = w1b + N1;
  unsigned short* ha  = w2b + N2;

  // fused fp32->bf16 conversion (x | w1 | w2)
  const long ntot = NX + N1 + N2;              // 246,251,520
  cvt_all<<<(int)(ntot / 2048), 256, 0, stream>>>(x, w1, w2, xb, w1b, w2b);

  // GEMM1 + bias + swiglu -> ha; 128x128 tiles, 16m x 45n per expert
  dim3 g1(720, 1, NE);
  gemm1_128<<<g1, 256, 0, stream>>>(xb, w1b, b1, ha);

  // GEMM2 + bias -> out (fp32 [T][2880]); unchanged
  dim3 g2((DIM_ / 320) * (TPE / 256), 1, NE);  // 72 per expert
  gemm2k<<<g2, 512, 0, stream>>>(ha, w2b, b2, (float*)d_out, TPE, DIM_);
}